// Round 14
// baseline (450.717 us; speedup 1.0000x reference)
//
#include <hip/hip_runtime.h>
#include <hip/hip_bf16.h>
#include <math.h>
#include <stdint.h>

// ---------------------------------------------------------------------------
// DiffusionCriterion, split per round-13 diagnosis:
//  * cost_kernel: 4 threads/row, 1000 blocks x 256 thr (4x parallelism of the
//    fused build). One streaming pass (quarter-row held in registers), quad
//    shuffle max/sum, gathers hit L2 hot. Writes Cmat + per-row argmin key +
//    (mx+log(sum)). Fixes: 3-pass L2 thrash (245MB->~90MB) + 12% occupancy.
//  * match_kernel: round-13 matching verbatim (measured-correct), but r[100]
//    loaded from Cmat (25x float4) instead of recomputed.
//  * finalize: mean over batch.
// ---------------------------------------------------------------------------

#define QN 500
#define TN 100
#define CN 256
#define DIFFSTEPS 100
#define NTHR 512

__device__ __forceinline__ float giou_xyxy(float ax1, float ay1, float ax2, float ay2,
                                           float bx1, float by1, float bx2, float by2) {
    float area1 = (ax2 - ax1) * (ay2 - ay1);
    float area2 = (bx2 - bx1) * (by2 - by1);
    float ltx = fmaxf(ax1, bx1), lty = fmaxf(ay1, by1);
    float rbx = fminf(ax2, bx2), rby = fminf(ay2, by2);
    float w = fmaxf(rbx - ltx, 0.f), h = fmaxf(rby - lty, 0.f);
    float inter = w * h;
    float uni = area1 + area2 - inter;
    float iou = inter / uni;
    float ex1 = fminf(ax1, bx1), ey1 = fminf(ay1, by1);
    float ex2 = fmaxf(ax2, bx2), ey2 = fmaxf(ay2, by2);
    float ew = fmaxf(ex2 - ex1, 0.f), eh = fmaxf(ey2 - ey1, 0.f);
    float ae = ew * eh;
    return iou - (ae - uni) / ae;
}

// Monotone order-preserving float->uint32 key (min float == min key).
__device__ __forceinline__ uint32_t fkey(float v) {
    uint32_t b = __float_as_uint(v);
    return (b & 0x80000000u) ? ~b : (b | 0x80000000u);
}

__device__ __forceinline__ unsigned long long u64min(unsigned long long a, unsigned long long b) {
    return (b < a) ? b : a;
}

// ---------------- cost kernel: 4 threads per row ----------------
// grid = B*QN*4/256 blocks. Quad lanes (tid%4==0..3) cooperate on one row.
__global__ __launch_bounds__(256, 4) void cost_kernel(
    const float* __restrict__ logits, const float* __restrict__ boxes,
    const int* __restrict__ labels, const float* __restrict__ tboxes,
    float* __restrict__ Cmat, unsigned long long* __restrict__ keys,
    float* __restrict__ mxls) {

    const int gid = blockIdx.x * 256 + threadIdx.x;
    const int rix = gid >> 2;          // global row index in [0, B*QN)
    const int l4  = gid & 3;           // lane within quad
    const int b   = rix / QN;
    const int q   = rix - b * QN;

    const float* lrow = logits + (size_t)rix * CN;

    // ---- stream my 64-float quarter into registers, compute max ----
    float4 f4[16];
    float mx = -INFINITY;
    #pragma unroll
    for (int j = 0; j < 16; ++j) {
        f4[j] = *(const float4*)(lrow + l4 * 64 + j * 4);
        mx = fmaxf(mx, fmaxf(fmaxf(f4[j].x, f4[j].y), fmaxf(f4[j].z, f4[j].w)));
    }
    mx = fmaxf(mx, __shfl_xor(mx, 1, 64));
    mx = fmaxf(mx, __shfl_xor(mx, 2, 64));    // quad max (exact)

    // ---- register-resident exp-sum (no second memory pass) ----
    float se = 0.f;
    #pragma unroll
    for (int j = 0; j < 16; ++j) {
        se += expf(f4[j].x - mx) + expf(f4[j].y - mx) +
              expf(f4[j].z - mx) + expf(f4[j].w - mx);
    }
    se += __shfl_xor(se, 1, 64);
    se += __shfl_xor(se, 2, 64);               // quad sum
    if (l4 == 0) mxls[rix] = mx + logf(se);
    float inv = 1.f / se;

    // ---- 25 targets per lane: gather + cost + store ----
    float4 pb = *(const float4*)(boxes + (size_t)rix * 4);
    float ax1 = pb.x - 0.5f * pb.z, ay1 = pb.y - 0.5f * pb.w;
    float ax2 = pb.x + 0.5f * pb.z, ay2 = pb.y + 0.5f * pb.w;

    float* Crow = Cmat + (size_t)rix * TN;
    float bv = INFINITY; int ba = -1;
    #pragma unroll
    for (int tt = 0; tt < 25; ++tt) {
        int t = l4 * 25 + tt;
        int cls = labels[b * TN + t];
        float4 tb = *(const float4*)(tboxes + ((size_t)b * TN + t) * 4);
        float e  = expf(lrow[cls] - mx);       // gather: row is L2-hot
        float cc = -(e * inv);
        float cb = fabsf(pb.x - tb.x) + fabsf(pb.y - tb.y) +
                   fabsf(pb.z - tb.z) + fabsf(pb.w - tb.w);
        float bx1 = tb.x - 0.5f * tb.z, by1 = tb.y - 0.5f * tb.w;
        float bx2 = tb.x + 0.5f * tb.z, by2 = tb.y + 0.5f * tb.w;
        float g  = giou_xyxy(ax1, ay1, ax2, ay2, bx1, by1, bx2, by2);
        float c  = cc + 5.f * cb - 2.f * g;
        Crow[t] = c;
        if (c < bv) { bv = c; ba = t; }        // strict <: first occurrence
    }
    // quad argmin with exact first-occurrence tie-break (flat idx in key)
    unsigned long long kk = ((unsigned long long)fkey(bv) << 32) |
                            (unsigned long long)(uint32_t)(q * TN + ba);
    kk = u64min(kk, __shfl_xor(kk, 1, 64));
    kk = u64min(kk, __shfl_xor(kk, 2, 64));
    if (l4 == 0) keys[rix] = kk;
}

// ---------------- match + loss kernel (round-13 logic, build removed) ------
__global__ __launch_bounds__(NTHR, 2) void match_kernel(
    const float* __restrict__ logits, const float* __restrict__ boxes,
    const int* __restrict__ labels, const float* __restrict__ tboxes,
    const int* __restrict__ ttime, const float* __restrict__ noise,
    const float* __restrict__ Cmat, const unsigned long long* __restrict__ keys,
    const float* __restrict__ mxls, float* __restrict__ per_img) {

    const int b = blockIdx.x;
    const int tid = threadIdx.x;

    __shared__ int    lbl_sh[TN];
    __shared__ float4 tb_sh[TN];
    __shared__ float  mxls_sh[QN];
    __shared__ int    srcS[TN], tgtS[TN];
    __shared__ unsigned long long wmin[2][8];   // parity double-buffer
    __shared__ float  pSum[8];
    __shared__ float  s_scale;

    if (tid < TN) {
        lbl_sh[tid] = labels[b * TN + tid];
        tb_sh[tid]  = *(const float4*)(tboxes + ((size_t)b * TN + tid) * 4);
    }
    if (tid == NTHR - 1) {
        int t = ttime[b];
        float step = (0.02f - 1e-4f) / (float)(DIFFSTEPS - 1);
        float acp = 1.f;
        for (int i2 = 0; i2 <= t; ++i2) acp *= (1.f - (1e-4f + step * (float)i2));
        s_scale = sqrtf(1.f - acp);
    }

    // ---- load my row + key (no recompute) ----
    float r[TN];
    bool  alive  = (tid < QN);
    uint32_t mykey  = 0xFFFFFFFFu;
    uint32_t myflat = 0xFFFFFFFFu;
    int   myarg = -1;

    if (alive) {
        const float* Crow = Cmat + ((size_t)b * QN + tid) * TN;
        #pragma unroll
        for (int j = 0; j < TN / 4; ++j) {
            float4 v = *(const float4*)(Crow + j * 4);
            r[j * 4 + 0] = v.x; r[j * 4 + 1] = v.y;
            r[j * 4 + 2] = v.z; r[j * 4 + 3] = v.w;
        }
        unsigned long long kk = keys[b * QN + tid];
        mykey  = (uint32_t)(kk >> 32);
        myflat = (uint32_t)kk;
        myarg  = (int)myflat - tid * TN;
        mxls_sh[tid] = mxls[b * QN + tid];
    }
    __syncthreads();

    unsigned long long m0 = ~0ull, m1 = ~0ull;  // alive-column bitmask

    // ---- greedy matching: TN sequential steps, 1 barrier each ----
    for (int k = 0; k < TN; ++k) {
        unsigned long long pk = ((unsigned long long)mykey << 32) | (unsigned long long)myflat;
        #pragma unroll
        for (int o = 1; o < 64; o <<= 1) {
            unsigned long long q = __shfl_xor(pk, o, 64);
            pk = (q < pk) ? q : pk;
        }
        if ((tid & 63) == 0) wmin[k & 1][tid >> 6] = pk;
        __syncthreads();
        unsigned long long best = wmin[k & 1][0];
        #pragma unroll
        for (int w = 1; w < 8; ++w) {
            unsigned long long q = wmin[k & 1][w];
            best = (q < best) ? q : best;
        }
        uint32_t flat = (uint32_t)best;
        int is = (int)(flat / TN);
        int js = (int)(flat - (uint32_t)is * TN);

        if (tid == is) {                        // unique winner records the pair
            srcS[k] = is; tgtS[k] = js;
            alive = false; mykey = 0xFFFFFFFFu; myflat = 0xFFFFFFFFu;
        }
        if (js < 64) m0 &= ~(1ull << js); else m1 &= ~(1ull << (js - 64));

        if (alive && myarg == js) {             // register-resident rescan
            float nbv = INFINITY; int nba = -1;
            #pragma unroll
            for (int jj = 0; jj < TN; ++jj) {
                bool ok = (jj < 64) ? (((m0 >> jj) & 1ull) != 0ull)
                                    : (((m1 >> (jj - 64)) & 1ull) != 0ull);
                float c = r[jj];
                if (ok && (c < nbv)) { nbv = c; nba = jj; }
            }
            myarg  = nba;
            mykey  = fkey(nbv);
            myflat = (uint32_t)(tid * TN + nba);
        }
    }
    __syncthreads();

    // ---- losses: one thread per matched pair ----
    float contrib = 0.f;
    if (tid < TN) {
        int i = srcS[tid], j = tgtS[tid];
        int cls = lbl_sh[j];
        float lc = logits[((size_t)b * QN + i) * CN + cls];
        float ce = mxls_sh[i] - lc;

        float4 sb = *(const float4*)(boxes + ((size_t)b * QN + i) * 4);
        float4 gb = tb_sh[j];
        float bb = fabsf(sb.x - gb.x) + fabsf(sb.y - gb.y) +
                   fabsf(sb.z - gb.z) + fabsf(sb.w - gb.w);

        float ax1 = sb.x - 0.5f * sb.z, ay1 = sb.y - 0.5f * sb.w;
        float ax2 = sb.x + 0.5f * sb.z, ay2 = sb.y + 0.5f * sb.w;
        float bx1 = gb.x - 0.5f * gb.z, by1 = gb.y - 0.5f * gb.w;
        float bx2 = gb.x + 0.5f * gb.z, by2 = gb.y + 0.5f * gb.w;
        float gi = giou_xyxy(ax1, ay1, ax2, ay2, bx1, by1, bx2, by2);

        float4 nz = *(const float4*)(noise + ((size_t)b * TN + j) * 4);
        float sc = s_scale;
        float d0 = sb.x - (gb.x + nz.x * sc), d1 = sb.y - (gb.y + nz.y * sc);
        float d2 = sb.z - (gb.z + nz.z * sc), d3 = sb.w - (gb.w + nz.w * sc);
        float df = d0 * d0 + d1 * d1 + d2 * d2 + d3 * d3;

        contrib = ce + 5.f * bb - 2.f * gi + 0.25f * df;
    }
    #pragma unroll
    for (int o = 1; o < 64; o <<= 1) contrib += __shfl_xor(contrib, o, 64);
    if ((tid & 63) == 0) pSum[tid >> 6] = contrib;
    __syncthreads();
    if (tid == 0) {
        float tot = 0.f;
        for (int w = 0; w < 8; ++w) tot += pSum[w];
        per_img[b] = 2.0f + tot / (float)TN;
    }
}

__global__ void finalize_kernel(const float* __restrict__ per_img, float* __restrict__ out, int B) {
    __shared__ float red[256];
    int tid = threadIdx.x;
    float v = (tid < B) ? per_img[tid] : 0.f;
    red[tid] = v;
    __syncthreads();
    for (int s = 128; s > 0; s >>= 1) {
        if (tid < s) red[tid] += red[tid + s];
        __syncthreads();
    }
    if (tid == 0) out[0] = red[0] / (float)B;
}

extern "C" void kernel_launch(void* const* d_in, const int* in_sizes, int n_in,
                              void* d_out, int out_size, void* d_ws, size_t ws_size,
                              hipStream_t stream) {
    const float* pred_logits = (const float*)d_in[0];
    const float* pred_boxes  = (const float*)d_in[1];
    const int*   tgt_labels  = (const int*)d_in[2];
    const float* tgt_boxes   = (const float*)d_in[3];
    const int*   tgt_time    = (const int*)d_in[4];
    const float* noise       = (const float*)d_in[5];
    float* out = (float*)d_out;

    const int B = in_sizes[4];                   // tgt_time: [B]

    // ws layout: Cmat | keys | mxls | per_img
    float* Cmat = (float*)d_ws;                                       // B*QN*TN f32
    unsigned long long* keys =
        (unsigned long long*)((char*)d_ws + (size_t)B * QN * TN * 4); // B*QN u64
    float* mxls = (float*)((char*)keys + (size_t)B * QN * 8);         // B*QN f32
    float* per_img = mxls + (size_t)B * QN;                           // B f32

    cost_kernel<<<(B * QN * 4) / 256, 256, 0, stream>>>(
        pred_logits, pred_boxes, tgt_labels, tgt_boxes, Cmat, keys, mxls);
    match_kernel<<<B, NTHR, 0, stream>>>(pred_logits, pred_boxes, tgt_labels,
                                         tgt_boxes, tgt_time, noise,
                                         Cmat, keys, mxls, per_img);
    finalize_kernel<<<1, 256, 0, stream>>>(per_img, out, B);
}

// Round 15
// 241.739 us; speedup vs baseline: 1.8645x; 1.8645x over previous
//
#include <hip/hip_runtime.h>
#include <hip/hip_bf16.h>
#include <math.h>
#include <stdint.h>

// ---------------------------------------------------------------------------
// DiffusionCriterion, column-parallel matching (round-14 diagnosis):
//  * cost_kernel: ONE WAVE PER ROW. Row logits in 4 regs/lane; shuffle-
//    butterfly max/sum; class gather via register __shfl (no memory gather,
//    no arrays -> no scratch spill, the R9/R13/R14 failure mode). Coalesced
//    row-major Cmat writes + mxls.
//  * init_cols_kernel: per-column argmin keys (coalesced scan).
//  * match_kernel: 1 wave/image, ZERO barriers. 100 col-keys in 2 regs/lane,
//    row-alive = 8 x u64 (static-indexed). Per step: 6-shuffle butterfly.
//    Col-rescans are rare (~22/image: E = alive_cols/alive_rows per step)
//    and wave-cooperative. Exact numpy flat-argmin tie-break via
//    (orderkey<<32|i*T+j) u64 min -- smallest flat index on ties.
//  * finalize: mean over batch.
// ---------------------------------------------------------------------------

#define QN 500
#define TN 100
#define CN 256
#define DIFFSTEPS 100
#define DEADKEY 0xFFFFFFFFFFFFFFFFull

__device__ __forceinline__ float giou_xyxy(float ax1, float ay1, float ax2, float ay2,
                                           float bx1, float by1, float bx2, float by2) {
    float area1 = (ax2 - ax1) * (ay2 - ay1);
    float area2 = (bx2 - bx1) * (by2 - by1);
    float ltx = fmaxf(ax1, bx1), lty = fmaxf(ay1, by1);
    float rbx = fminf(ax2, bx2), rby = fminf(ay2, by2);
    float w = fmaxf(rbx - ltx, 0.f), h = fmaxf(rby - lty, 0.f);
    float inter = w * h;
    float uni = area1 + area2 - inter;
    float iou = inter / uni;
    float ex1 = fminf(ax1, bx1), ey1 = fminf(ay1, by1);
    float ex2 = fmaxf(ax2, bx2), ey2 = fmaxf(ay2, by2);
    float ew = fmaxf(ex2 - ex1, 0.f), eh = fmaxf(ey2 - ey1, 0.f);
    float ae = ew * eh;
    return iou - (ae - uni) / ae;
}

// Monotone order-preserving float->uint32 key (min float == min key).
__device__ __forceinline__ uint32_t fkey(float v) {
    uint32_t b = __float_as_uint(v);
    return (b & 0x80000000u) ? ~b : (b | 0x80000000u);
}

__device__ __forceinline__ unsigned long long packkey(float v, int flat) {
    return ((unsigned long long)fkey(v) << 32) | (unsigned long long)(uint32_t)flat;
}

// ---------------- cost kernel: one wave per row ----------------
// grid = B*QN/4 blocks x 256 thr (4 waves/block).
__global__ __launch_bounds__(256) void cost_kernel(
    const float* __restrict__ logits, const float* __restrict__ boxes,
    const int* __restrict__ labels, const float* __restrict__ tboxes,
    float* __restrict__ Cmat, float* __restrict__ mxls) {

    const int wid = (blockIdx.x << 2) + (threadIdx.x >> 6);  // row id in [0, B*QN)
    const int l   = threadIdx.x & 63;
    const int b   = wid / QN;

    const float* lrow = logits + (size_t)wid * CN;
    float4 lv = *(const float4*)(lrow + l * 4);    // classes 4l..4l+3 in regs

    float mx = fmaxf(fmaxf(lv.x, lv.y), fmaxf(lv.z, lv.w));
    #pragma unroll
    for (int o = 1; o < 64; o <<= 1) mx = fmaxf(mx, __shfl_xor(mx, o, 64));

    float se = expf(lv.x - mx) + expf(lv.y - mx) + expf(lv.z - mx) + expf(lv.w - mx);
    #pragma unroll
    for (int o = 1; o < 64; o <<= 1) se += __shfl_xor(se, o, 64);

    if (l == 0) mxls[wid] = mx + logf(se);
    float inv = 1.f / se;

    float4 pb = *(const float4*)(boxes + (size_t)wid * 4);
    float ax1 = pb.x - 0.5f * pb.z, ay1 = pb.y - 0.5f * pb.w;
    float ax2 = pb.x + 0.5f * pb.z, ay2 = pb.y + 0.5f * pb.w;

    #pragma unroll
    for (int half = 0; half < 2; ++half) {
        int t = half * 64 + l;
        bool valid = (t < TN);
        int cls = valid ? labels[b * TN + t] : 0;
        float4 tb = make_float4(0.f, 0.f, 0.f, 0.f);
        if (valid) tb = *(const float4*)(tboxes + ((size_t)b * TN + t) * 4);
        int sl = cls >> 2, ss = cls & 3;
        // register gather: all lanes participate in the shfl
        float g0 = __shfl(lv.x, sl, 64);
        float g1 = __shfl(lv.y, sl, 64);
        float g2 = __shfl(lv.z, sl, 64);
        float g3 = __shfl(lv.w, sl, 64);
        if (valid) {
            float lc = (ss == 0) ? g0 : (ss == 1) ? g1 : (ss == 2) ? g2 : g3;
            float e  = expf(lc - mx);
            float cc = -(e * inv);
            float cb = fabsf(pb.x - tb.x) + fabsf(pb.y - tb.y) +
                       fabsf(pb.z - tb.z) + fabsf(pb.w - tb.w);
            float bx1 = tb.x - 0.5f * tb.z, by1 = tb.y - 0.5f * tb.w;
            float bx2 = tb.x + 0.5f * tb.z, by2 = tb.y + 0.5f * tb.w;
            float g  = giou_xyxy(ax1, ay1, ax2, ay2, bx1, by1, bx2, by2);
            Cmat[(size_t)wid * TN + t] = cc + 5.f * cb - 2.f * g;   // coalesced
        }
    }
}

// ---------------- initial per-column argmin keys ----------------
// grid = B blocks x 128 thr; thread t < 100 scans column t (coalesced per q).
__global__ __launch_bounds__(128) void init_cols_kernel(
    const float* __restrict__ Cmat, unsigned long long* __restrict__ kcol) {
    const int b = blockIdx.x;
    const int t = threadIdx.x;
    if (t >= TN) return;
    const float* Cb = Cmat + (size_t)b * QN * TN;
    float bv = INFINITY; int ba = 0;
    for (int q = 0; q < QN; ++q) {
        float c = Cb[(size_t)q * TN + t];
        if (c < bv) { bv = c; ba = q; }    // strict <: smallest q on ties
    }
    kcol[b * TN + t] = packkey(bv, ba * TN + t);
}

// ---------------- match + loss: ONE wave per image, zero barriers ----------
__global__ __launch_bounds__(64) void match_kernel(
    const float* __restrict__ logits, const float* __restrict__ boxes,
    const int* __restrict__ labels, const float* __restrict__ tboxes,
    const int* __restrict__ ttime, const float* __restrict__ noise,
    const float* __restrict__ Cmat, const unsigned long long* __restrict__ kcol,
    const float* __restrict__ mxls, float* __restrict__ per_img) {

    const int b = blockIdx.x;
    const int l = threadIdx.x;   // 0..63
    const float* Cb = Cmat + (size_t)b * QN * TN;

    // lane l owns columns l and 64+l (latter only for l < 36)
    unsigned long long kc0 = kcol[b * TN + l];
    unsigned long long kc1 = (l < TN - 64) ? kcol[b * TN + 64 + l] : DEADKEY;
    int ar0 = (int)((uint32_t)kc0) / TN;                       // argmin row
    int ar1 = (kc1 != DEADKEY) ? (int)((uint32_t)kc1) / TN : -1;

    // alive-row bitmask, replicated per lane; static indexing only
    unsigned long long ra[8];
    #pragma unroll
    for (int m = 0; m < 8; ++m) ra[m] = ~0ull;
    ra[7] = (1ull << (QN - 448)) - 1;                          // rows 500..511 dead

    int pi0 = 0, pj0 = 0, pi1 = 0, pj1 = 0;                    // recorded pairs

    for (int k = 0; k < TN; ++k) {
        unsigned long long pk = (kc0 < kc1) ? kc0 : kc1;
        #pragma unroll
        for (int o = 1; o < 64; o <<= 1) {
            unsigned long long q2 = __shfl_xor(pk, o, 64);
            pk = (q2 < pk) ? q2 : pk;
        }
        int flat = (int)(uint32_t)pk;
        int i = flat / TN;
        int j = flat - i * TN;

        if (k < 64) { if (l == k)      { pi0 = i; pj0 = j; } }
        else        { if (l == k - 64) { pi1 = i; pj1 = j; } }

        // kill column j
        if (j < 64) { if (l == j)      kc0 = DEADKEY; }
        else        { if (l == j - 64) kc1 = DEADKEY; }

        // kill row i (static-indexed update)
        int im = i >> 6; unsigned long long ib = 1ull << (i & 63);
        #pragma unroll
        for (int m = 0; m < 8; ++m) if (m == im) ra[m] &= ~ib;

        // rescan columns whose argmin row just died (rare: ~0.2/step)
        bool need0 = (kc0 != DEADKEY) && (ar0 == i);
        bool need1 = (kc1 != DEADKEY) && (ar1 == i);

        unsigned long long bal = __ballot(need0);
        while (bal) {
            int src = (int)__ffsll(bal) - 1;
            int jj = src;
            unsigned long long best = DEADKEY;
            #pragma unroll
            for (int m = 0; m < 8; ++m) {
                int q = m * 64 + l;
                if (((ra[m] >> l) & 1ull) != 0ull) {
                    float c = Cb[(size_t)q * TN + jj];
                    unsigned long long kk = packkey(c, q * TN + jj);
                    best = (kk < best) ? kk : best;
                }
            }
            #pragma unroll
            for (int o = 1; o < 64; o <<= 1) {
                unsigned long long q2 = __shfl_xor(best, o, 64);
                best = (q2 < best) ? q2 : best;
            }
            if (l == src) { kc0 = best; ar0 = (int)((uint32_t)best) / TN; }
            bal &= bal - 1;
        }
        bal = __ballot(need1);
        while (bal) {
            int src = (int)__ffsll(bal) - 1;
            int jj = 64 + src;
            unsigned long long best = DEADKEY;
            #pragma unroll
            for (int m = 0; m < 8; ++m) {
                int q = m * 64 + l;
                if (((ra[m] >> l) & 1ull) != 0ull) {
                    float c = Cb[(size_t)q * TN + jj];
                    unsigned long long kk = packkey(c, q * TN + jj);
                    best = (kk < best) ? kk : best;
                }
            }
            #pragma unroll
            for (int o = 1; o < 64; o <<= 1) {
                unsigned long long q2 = __shfl_xor(best, o, 64);
                best = (q2 < best) ? q2 : best;
            }
            if (l == src) { kc1 = best; ar1 = (int)((uint32_t)best) / TN; }
            bal &= bal - 1;
        }
    }

    // ---- losses (same wave; round-10 verified formulas) ----
    int t = ttime[b];
    float step = (0.02f - 1e-4f) / (float)(DIFFSTEPS - 1);
    float acp = 1.f;
    for (int i2 = 0; i2 <= t; ++i2) acp *= (1.f - (1e-4f + step * (float)i2));
    float scale = sqrtf(1.f - acp);

    float contrib = 0.f;
    #pragma unroll
    for (int rnd = 0; rnd < 2; ++rnd) {
        int i = rnd ? pi1 : pi0, j = rnd ? pj1 : pj0;
        if (rnd == 0 || l < TN - 64) {
            int cls = labels[b * TN + j];
            float lc = logits[((size_t)b * QN + i) * CN + cls];
            float ce = mxls[b * QN + i] - lc;   // == -(lc - mx - logsum)

            float4 sb = *(const float4*)(boxes + ((size_t)b * QN + i) * 4);
            float4 gb = *(const float4*)(tboxes + ((size_t)b * TN + j) * 4);
            float bb = fabsf(sb.x - gb.x) + fabsf(sb.y - gb.y) +
                       fabsf(sb.z - gb.z) + fabsf(sb.w - gb.w);

            float ax1 = sb.x - 0.5f * sb.z, ay1 = sb.y - 0.5f * sb.w;
            float ax2 = sb.x + 0.5f * sb.z, ay2 = sb.y + 0.5f * sb.w;
            float bx1 = gb.x - 0.5f * gb.z, by1 = gb.y - 0.5f * gb.w;
            float bx2 = gb.x + 0.5f * gb.z, by2 = gb.y + 0.5f * gb.w;
            float gi = giou_xyxy(ax1, ay1, ax2, ay2, bx1, by1, bx2, by2);

            float4 nz = *(const float4*)(noise + ((size_t)b * TN + j) * 4);
            float d0 = sb.x - (gb.x + nz.x * scale), d1 = sb.y - (gb.y + nz.y * scale);
            float d2 = sb.z - (gb.z + nz.z * scale), d3 = sb.w - (gb.w + nz.w * scale);
            float df = d0 * d0 + d1 * d1 + d2 * d2 + d3 * d3;

            contrib += ce + 5.f * bb - 2.f * gi + 0.25f * df;
        }
    }
    #pragma unroll
    for (int o = 1; o < 64; o <<= 1) contrib += __shfl_xor(contrib, o, 64);
    if (l == 0) per_img[b] = 2.0f + contrib / (float)TN;
}

__global__ void finalize_kernel(const float* __restrict__ per_img, float* __restrict__ out, int B) {
    __shared__ float red[256];
    int tid = threadIdx.x;
    float v = (tid < B) ? per_img[tid] : 0.f;
    red[tid] = v;
    __syncthreads();
    for (int s = 128; s > 0; s >>= 1) {
        if (tid < s) red[tid] += red[tid + s];
        __syncthreads();
    }
    if (tid == 0) out[0] = red[0] / (float)B;
}

extern "C" void kernel_launch(void* const* d_in, const int* in_sizes, int n_in,
                              void* d_out, int out_size, void* d_ws, size_t ws_size,
                              hipStream_t stream) {
    const float* pred_logits = (const float*)d_in[0];
    const float* pred_boxes  = (const float*)d_in[1];
    const int*   tgt_labels  = (const int*)d_in[2];
    const float* tgt_boxes   = (const float*)d_in[3];
    const int*   tgt_time    = (const int*)d_in[4];
    const float* noise       = (const float*)d_in[5];
    float* out = (float*)d_out;

    const int B = in_sizes[4];                   // tgt_time: [B]

    // ws layout: Cmat | mxls | kcol | per_img (all naturally 8B-aligned)
    float* Cmat = (float*)d_ws;                                   // B*QN*TN f32
    float* mxls = Cmat + (size_t)B * QN * TN;                     // B*QN f32
    unsigned long long* kcol =
        (unsigned long long*)(mxls + (size_t)B * QN);             // B*TN u64
    float* per_img = (float*)(kcol + (size_t)B * TN);             // B f32

    cost_kernel<<<(B * QN) / 4, 256, 0, stream>>>(
        pred_logits, pred_boxes, tgt_labels, tgt_boxes, Cmat, mxls);
    init_cols_kernel<<<B, 128, 0, stream>>>(Cmat, kcol);
    match_kernel<<<B, 64, 0, stream>>>(pred_logits, pred_boxes, tgt_labels,
                                       tgt_boxes, tgt_time, noise,
                                       Cmat, kcol, mxls, per_img);
    finalize_kernel<<<1, 256, 0, stream>>>(per_img, out, B);
}